// Round 9
// baseline (2177.126 us; speedup 1.0000x reference)
//
// HierarchicalPattern — rev16. R15 post-mortem: 2-deep gload_lds pipeline was
// neutral (842->903) — fifth straight round where a counter-verified fix left
// mask duration pinned. Table: 256thr=452 (even spilled!), 512thr=469-503,
// 1024thr=842-903 — duration tracks block size, not inner code. And the
// launch residual (total - mask) = 250-305 µs across NINE rounds and THREE
// different feat kernels — a constant across different programs is overhead,
// not program cost (feat-invariant vs harness/launch ambiguity).
// rev16 splits that ambiguity AND reverts mask to best-known form: ONE
// cooperative kernel (1024 blk x 512 thr, lb(512,8) => <=64 VGPR for
// guaranteed 4-blk/CU co-residency): feat phase = feat_v14 wave-tasks
// (byte-equivalent), grid.sync(), mask phase = R10/R11-proven 512-thr
// structure (TQ=4, acc 32 f32, bisection, bitmap) looped r=0..3 with
// g = r*1024+bid — all blocks stream the SAME batch per round (4 MB gfT =
// one XCD L2). Tell: total - fused-dispatch-dur measures harness overhead
// directly. A: gap~0, total ~560-620 => residual was launch overhead (win).
// B: gap~250 => unremovable; R17 attacks mask phase with known floor.
#include <hip/hip_runtime.h>
#include <hip/hip_fp16.h>
#include <hip/hip_cooperative_groups.h>
#include <cstdint>

namespace cg = cooperative_groups;

#define SEQ 4096
#define NB 4
#define DMODEL 1024
#define ID 64
#define LW 16
#define GK 32
#define TQ 4

#define NEG_INF (-__builtin_inff())
#define MASKED4 0xFBFFFBFFu
#define FMAT (NB * SEQ * ID)          // floats per feature matrix (4 MiB)

typedef _Float16 f16x8 __attribute__((ext_vector_type(8)));
typedef float f32x4 __attribute__((ext_vector_type(4)));

// ---------------- Fused cooperative kernel -----------------------------------
// Phase F (feat): block bid owns x rows [bid*16, bid*16+16); wave w: half=w&1
// (0=lf, 1=gfT), ch=w>>1 (16-col quarter). Identical math to feat_v14.
// grid.sync().
// Phase M (mask): r = 0..3, g = r*1024 + bid; b = g>>10, q0 = (g&1023)*TQ.
// R10/R11-verified structure: 512 thr, keys k = 2048c+4t+j (c in {0,1}),
// acc[2][4][4] = 32 f32; float-domain bisection; LDS bitmap; single-pass fill.
__global__ __launch_bounds__(512, 8)
void hp_fused_v16(const unsigned short* __restrict__ xu,
                  const unsigned short* __restrict__ Wlu,
                  const unsigned short* __restrict__ Wgu,
                  float* __restrict__ lf, float* __restrict__ gfT,
                  unsigned short* __restrict__ out)
{
    __shared__ float qv[TQ][ID];                  // 1 KiB
    __shared__ float lq[TQ][ID];                  // 1 KiB
    __shared__ unsigned long long red[4][8];      // buf0,buf1,greater,equal
    __shared__ unsigned int bitmap[TQ][SEQ / 32]; // 2 KiB selection bitmap
    __shared__ float lsc[TQ][LW];
    __shared__ unsigned char tm[512];             // rare tie path: 8 keys/thr

    const int tid = threadIdx.x;
    const int lane = tid & 63, w = tid >> 6;      // 8 waves
    const int bid = blockIdx.x;                   // 1024 blocks

    // ==== Phase F: features ==================================================
    {
        const long row0 = (long)bid * 16;
        const int half = w & 1;
        const int ch = w >> 1;                    // 0..3, 16 cols each
        const _Float16* xp = (const _Float16*)xu;
        const _Float16* Wp = (const _Float16*)(half ? Wgu : Wlu);

        const int lr = lane & 15;      // row-in-tile (A) / col-in-tile (B,D)
        const int kg = lane >> 4;      // k-group: k offset kg*8

        const _Float16* ap = xp + (row0 + lr) * DMODEL + kg * 8;
        const _Float16* bp = Wp + (long)(ch * 16 + lr) * DMODEL + kg * 8;

        f32x4 acc = (f32x4){0.f, 0.f, 0.f, 0.f};
#pragma unroll 4
        for (int k0 = 0; k0 < DMODEL; k0 += 32) {
            f16x8 av = *(const f16x8*)(ap + k0);
            f16x8 bv = *(const f16x8*)(bp + k0);
            acc = __builtin_amdgcn_mfma_f32_16x16x32_f16(av, bv, acc, 0, 0, 0);
        }
        if (!half) {        // lf[s][d]
#pragma unroll
            for (int r = 0; r < 4; r++)
                lf[(row0 + kg * 4 + r) * ID + ch * 16 + lr] = acc[r];
        } else {            // gfT[b][d][s]: float4 along s
            const int bb = (int)(row0 >> 12), s0 = (int)(row0 & 4095);
            float4 st = make_float4(acc[0], acc[1], acc[2], acc[3]);
            *(float4*)(gfT + ((long)bb * ID + ch * 16 + lr) * SEQ + s0 + kg * 4) = st;
        }
    }

    __threadfence();
    cg::this_grid().sync();

    // ==== Phase M: mask, 4 q-groups per block ================================
#pragma unroll 1
    for (int r = 0; r < 4; ++r) {
        const int g = r * 1024 + bid;             // all blocks on same batch
        const int b = g >> 10;
        const int q0 = (g & 1023) * TQ;
        const float* gTb = gfT + (long)b * ID * SEQ;
        const float* lfb = lf + (long)b * SEQ * ID;

        if (tid < 256) {   // qv[qi][d] = gfT[b][d][q0+qi]; lq from lf rows
            int d = tid >> 2, qi = tid & 3;
            qv[qi][d] = gTb[(long)d * SEQ + q0 + qi];
            int qi2 = tid >> 6, d2 = tid & 63;
            lq[qi2][d2] = lfb[(long)(q0 + qi2) * ID + d2];
        }
        ((unsigned int*)bitmap)[tid] = 0u;        // 512 words exactly
        __syncthreads();

        // ---- Phase 1: register-resident scores, 2-stream 1-deep prefetch ----
        float acc[2][4][TQ];                      // [c][j][qi] = 32 f32
#pragma unroll
        for (int c = 0; c < 2; c++)
#pragma unroll
            for (int j = 0; j < 4; j++)
#pragma unroll
                for (int qi = 0; qi < TQ; qi++) acc[c][j][qi] = 0.f;

        const float4* gT4 = (const float4*)gTb;
        float4 ka = gT4[tid], kb = gT4[512 + tid];
#pragma unroll 1
        for (int d = 0; d < ID; d++) {
            float4 na, nb;
            if (d + 1 < ID) {
                na = gT4[((d + 1) << 10) + tid];
                nb = gT4[((d + 1) << 10) + 512 + tid];
            }
            float qd[TQ];
#pragma unroll
            for (int qi = 0; qi < TQ; qi++) qd[qi] = qv[qi][d];  // uniform
#pragma unroll
            for (int qi = 0; qi < TQ; qi++) {
                acc[0][0][qi] = fmaf(ka.x, qd[qi], acc[0][0][qi]);
                acc[0][1][qi] = fmaf(ka.y, qd[qi], acc[0][1][qi]);
                acc[0][2][qi] = fmaf(ka.z, qd[qi], acc[0][2][qi]);
                acc[0][3][qi] = fmaf(ka.w, qd[qi], acc[0][3][qi]);
                acc[1][0][qi] = fmaf(kb.x, qd[qi], acc[1][0][qi]);
                acc[1][1][qi] = fmaf(kb.y, qd[qi], acc[1][1][qi]);
                acc[1][2][qi] = fmaf(kb.z, qd[qi], acc[1][2][qi]);
                acc[1][3][qi] = fmaf(kb.w, qd[qi], acc[1][3][qi]);
            }
            ka = na; kb = nb;
        }

        // ---- Phase 2a: in-place keys: sv = banned ? -1 : relu(s) ------------
#pragma unroll
        for (int c = 0; c < 2; c++)
#pragma unroll
            for (int j = 0; j < 4; j++) {
                const int k = 2048 * c + 4 * tid + j;
#pragma unroll
                for (int qi = 0; qi < TQ; qi++) {
                    const int q = q0 + qi;
                    const bool banned = (k <= q) && (k >= q - (LW - 1));
                    acc[c][j][qi] = banned ? -1.0f : fmaxf(acc[c][j][qi], 0.f);
                }
            }

        // ---- Phase 2b: bisection for m32 (float-domain, R9-R15 verified) ----
        unsigned int lo[TQ], hi[TQ];
#pragma unroll
        for (int qi = 0; qi < TQ; qi++) { lo[qi] = 0u; hi[qi] = 0x7F800000u; }

#pragma unroll 1
        for (int it = 0; it < 31; ++it) {
            unsigned long long pc = 0ull;
#pragma unroll
            for (int qi = 0; qi < TQ; qi++) {
                const unsigned int mid = lo[qi] + ((hi[qi] - lo[qi]) >> 1);
                const float tf = __uint_as_float(mid - 1u);
                int cnt = 0;
#pragma unroll
                for (int c = 0; c < 2; c++)
#pragma unroll
                    for (int j = 0; j < 4; j++)
                        cnt += __popcll(__ballot(acc[c][j][qi] >= tf));
                pc |= (unsigned long long)(unsigned int)cnt << (16 * qi);
            }
            if (lane == 0) red[it & 1][w] = pc;
            __syncthreads();
            unsigned long long tot = 0ull;
#pragma unroll
            for (int ww = 0; ww < 8; ww++) tot += red[it & 1][ww];
#pragma unroll
            for (int qi = 0; qi < TQ; qi++) {
                const unsigned int mid = lo[qi] + ((hi[qi] - lo[qi]) >> 1);
                const unsigned int cnt =
                    (unsigned int)((tot >> (16 * qi)) & 0xFFFFull);
                if (cnt >= GK) lo[qi] = mid; else hi[qi] = mid;
            }
        }

        // ---- Phase 2c: C1 = #{u > m32}, T = #{u == m32} ---------------------
        int T[TQ], need[TQ];
        {
            unsigned long long pg = 0ull, pe = 0ull;
#pragma unroll
            for (int qi = 0; qi < TQ; qi++) {
                const float tg = __uint_as_float(lo[qi]);
                const unsigned int eb = lo[qi] - 1u;
                int cg = 0, ce = 0;
#pragma unroll
                for (int c = 0; c < 2; c++)
#pragma unroll
                    for (int j = 0; j < 4; j++) {
                        const float v = acc[c][j][qi];
                        cg += __popcll(__ballot(v >= tg));
                        ce += __popcll(__ballot(__float_as_uint(v) == eb));
                    }
                pg |= (unsigned long long)(unsigned int)cg << (16 * qi);
                pe |= (unsigned long long)(unsigned int)ce << (16 * qi);
            }
            if (lane == 0) { red[2][w] = pg; red[3][w] = pe; }
            __syncthreads();
            unsigned long long tg = 0ull, te = 0ull;
#pragma unroll
            for (int ww = 0; ww < 8; ww++) { tg += red[2][ww]; te += red[3][ww]; }
#pragma unroll
            for (int qi = 0; qi < TQ; qi++) {
                const int c1 = (int)((tg >> (16 * qi)) & 0xFFFFull);
                T[qi]    = (int)((te >> (16 * qi)) & 0xFFFFull);
                need[qi] = GK - c1;           // >= 1; T >= need guaranteed
            }
        }

        // ---- Phase 2d: mark selections in bitmap ----------------------------
#pragma unroll
        for (int qi = 0; qi < TQ; qi++) {
            const bool allties = (T[qi] == need[qi]);
            const float tg = __uint_as_float(lo[qi]);
            const unsigned int eb = lo[qi] - 1u;
#pragma unroll
            for (int c = 0; c < 2; c++)
#pragma unroll
                for (int j = 0; j < 4; j++) {
                    const float v = acc[c][j][qi];
                    const bool sel_ = (v >= tg)
                                    | (allties & (__float_as_uint(v) == eb));
                    if (sel_) {
                        const int k = 2048 * c + 4 * tid + j;
                        atomicOr(&bitmap[qi][k >> 5], 1u << (k & 31));
                    }
                }
        }

        // Rare exact-tie path: `need` smallest-k ties ascending (c,t,j).
#pragma unroll 1
        for (int qi = 0; qi < TQ; qi++) {
            if (T[qi] > need[qi]) {       // block-uniform (from shared tot)
                const unsigned int eb = lo[qi] - 1u;
                unsigned int m8 = 0u;
#pragma unroll
                for (int c = 0; c < 2; c++)
#pragma unroll
                    for (int j = 0; j < 4; j++)
                        if (__float_as_uint(acc[c][j][qi]) == eb)
                            m8 |= 1u << (c * 4 + j);
                tm[tid] = (unsigned char)m8;
                __syncthreads();
                if (tid == 0) {
                    int taken = 0;
                    for (int c = 0; c < 2 && taken < need[qi]; c++)
                        for (int t = 0; t < 512 && taken < need[qi]; t++) {
                            const unsigned int nib =
                                ((unsigned int)tm[t] >> (c * 4)) & 15u;
                            for (int j = 0; j < 4 && taken < need[qi]; j++)
                                if ((nib >> j) & 1u) {
                                    const int k = 2048 * c + 4 * t + j;
                                    atomicOr(&bitmap[qi][k >> 5], 1u << (k & 31));
                                    taken++;
                                }
                        }
                }
                __syncthreads();
            }
        }

        // ---- local window: 16 scores per query, stable top-ks ---------------
        if (tid < TQ * LW) {
            int qi = tid >> 4, wnd = tid & 15;
            int q = q0 + qi;
            int win = q - (LW - 1) + wnd;
            float v = NEG_INF;
            if (win >= 0) {
                const float4* kr = (const float4*)(lfb + (long)win * ID);
                float s = 0.f;
#pragma unroll
                for (int d = 0; d < 16; d++) {
                    float4 kvv = kr[d];
                    const float4 qd = *(const float4*)&lq[qi][d * 4];
                    s = fmaf(kvv.x, qd.x, s); s = fmaf(kvv.y, qd.y, s);
                    s = fmaf(kvv.z, qd.z, s); s = fmaf(kvv.w, qd.w, s);
                }
                v = fmaxf(s, 0.f);
            }
            lsc[qi][wnd] = v;
        }
        __syncthreads();
        if (tid < TQ) {
            int qi = tid, q = q0 + qi;
            int L = (q + 1 < LW) ? q + 1 : LW;
            int ks = L / 5; if (ks < 1) ks = 1;   // == max(1, int(L*0.2))
            for (int t = 0; t < ks; t++) {
                float best = NEG_INF; int bi = 0;
                for (int wnd = 0; wnd < LW; wnd++) {
                    float v = lsc[qi][wnd];
                    if (v > best) { best = v; bi = wnd; }
                }
                lsc[qi][bi] = NEG_INF;
                const int win = q - (LW - 1) + bi;
                atomicOr(&bitmap[qi][win >> 5], 1u << (win & 31));
            }
        }
        __syncthreads();

        // ---- output: single-pass fill from bitmap ---------------------------
        uint4* orow = (uint4*)(out + ((long)b * SEQ + q0) * SEQ);
#pragma unroll
        for (int i = 0; i < TQ * SEQ / 8 / 512; i++) {  // 4 iters, 2048 uint4
            const int li = i * 512 + tid;
            const int qi = li >> 9;          // 512 uint4 per row
            const int w8 = li & 511;
            const unsigned int bits =
                (bitmap[qi][w8 >> 2] >> ((w8 & 3) * 8)) & 0xFFu;
            uint4 v;
            v.x = MASKED4 & ~(((bits &   1u) ? 0x0000FFFFu : 0u) |
                              ((bits &   2u) ? 0xFFFF0000u : 0u));
            v.y = MASKED4 & ~(((bits &   4u) ? 0x0000FFFFu : 0u) |
                              ((bits &   8u) ? 0xFFFF0000u : 0u));
            v.z = MASKED4 & ~(((bits &  16u) ? 0x0000FFFFu : 0u) |
                              ((bits &  32u) ? 0xFFFF0000u : 0u));
            v.w = MASKED4 & ~(((bits &  64u) ? 0x0000FFFFu : 0u) |
                              ((bits & 128u) ? 0xFFFF0000u : 0u));
            orow[li] = v;
        }
        __syncthreads();   // protect bitmap/lq/lsc reuse by next q-group
    }
}

extern "C" void kernel_launch(void* const* d_in, const int* in_sizes, int n_in,
                              void* d_out, int out_size, void* d_ws, size_t ws_size,
                              hipStream_t stream) {
    const unsigned short* x  = (const unsigned short*)d_in[0];
    const unsigned short* Wl = (const unsigned short*)d_in[1];
    // d_in[2] = W_medium: dead in the reference — skipped.
    const unsigned short* Wg = (const unsigned short*)d_in[3];
    unsigned short* out = (unsigned short*)d_out;

    float* lf  = (float*)d_ws;                        // 4 MiB, row-major
    float* gfT = lf + (long)FMAT;                     // 4 MiB, [b][d][s]

    void* kargs[] = {(void*)&x, (void*)&Wl, (void*)&Wg,
                     (void*)&lf, (void*)&gfT, (void*)&out};
    hipLaunchCooperativeKernel((const void*)hp_fused_v16,
                               dim3(NB * SEQ / 16), dim3(512),
                               kargs, 0, stream);
}

// Round 10
// 720.715 us; speedup vs baseline: 3.0208x; 3.0208x over previous
//
// HierarchicalPattern — rev17 (consolidation). R16 post-mortem: lb(512,8)
// forced VGPR=32 < acc -> worst spill (WRITE 1.5 GB, 1971 µs). But the single
// dispatch measured the harness constant: total - kernel = 206 µs fixed
// overhead. Budget accounting: R11 (best, 735 total) = mask 469 + feat ~60 +
// overhead ~206. Session facts: mask tracks block size (256t=452, 512t=469,
// 1024t=842), is invariant to inner restructuring, and the ~50-live-f32 spill
// wall blocks every deeper-tiling variant. No counter-backed lever predicts
// >10% on mask -> consolidate to the measured optimum: feat_v14 + R11's mask
// verbatim, plus the one innocent R13 improvement: qvT[d][qi] transposed
// broadcast (2 uniform ds_read_b128/d instead of 4 ds_read_b32; R13's
// regression was the acc-split spill, not qvT). lb(512,2) as in R11.
// Predict: mask 440-470 (clean signature: FETCH ~26 MB, WRITE ~131 MB,
// VGPR ~44), total ~700-740 = structural floor given the 206 µs constant.
#include <hip/hip_runtime.h>
#include <hip/hip_fp16.h>
#include <cstdint>

#define SEQ 4096
#define NB 4
#define DMODEL 1024
#define ID 64
#define LW 16
#define GK 32
#define TQ 4

#define NEG_INF (-__builtin_inff())
#define MASKED4 0xFBFFFBFFu
#define FMAT (NB * SEQ * ID)          // floats per feature matrix (4 MiB)

typedef _Float16 f16x8 __attribute__((ext_vector_type(8)));
typedef float f32x4 __attribute__((ext_vector_type(4)));

// ---------------- Kernel 1: lf + gfT via MFMA (fp16 in, f32 out) -------------
// feat_v14 verbatim (proven; residual analysis puts it ~60 µs, floor ~30).
// grid 1024 x 512thr; wave w: half=w&1 (0=lf,1=gfT), ch=w>>1 (16-col quarter).
// D-layout col=l&15, row=(l>>4)*4+reg (verified R10+).
__global__ __launch_bounds__(512)
void hp_feat_v14(const unsigned short* __restrict__ xu,
                 const unsigned short* __restrict__ Wlu,
                 const unsigned short* __restrict__ Wgu,
                 float* __restrict__ lf, float* __restrict__ gfT)
{
    const int tid = threadIdx.x;
    const int lane = tid & 63, w = tid >> 6;      // 8 waves
    const long row0 = (long)blockIdx.x * 16;
    const int half = w & 1;
    const int ch = w >> 1;                        // 0..3, 16 cols each
    const _Float16* xp = (const _Float16*)xu;
    const _Float16* Wp = (const _Float16*)(half ? Wgu : Wlu);

    const int lr = lane & 15;          // row-in-tile (A) / col-in-tile (B,D)
    const int kg = lane >> 4;          // k-group: k offset kg*8

    const _Float16* ap = xp + (row0 + lr) * DMODEL + kg * 8;
    const _Float16* bp = Wp + (long)(ch * 16 + lr) * DMODEL + kg * 8;

    f32x4 acc = (f32x4){0.f, 0.f, 0.f, 0.f};

#pragma unroll 4
    for (int k0 = 0; k0 < DMODEL; k0 += 32) {
        f16x8 av = *(const f16x8*)(ap + k0);
        f16x8 bv = *(const f16x8*)(bp + k0);
        acc = __builtin_amdgcn_mfma_f32_16x16x32_f16(av, bv, acc, 0, 0, 0);
    }

    if (!half) {        // lf[s][d]: 16 lanes = 16 consecutive d
#pragma unroll
        for (int r = 0; r < 4; r++)
            lf[(row0 + kg * 4 + r) * ID + ch * 16 + lr] = acc[r];
    } else {            // gfT[b][d][s]: float4 along s
        const int bb = (int)(row0 >> 12), s0 = (int)(row0 & 4095);
        float4 st = make_float4(acc[0], acc[1], acc[2], acc[3]);
        *(float4*)(gfT + ((long)bb * ID + ch * 16 + lr) * SEQ + s0 + kg * 4) = st;
    }
}

// ---------------- Kernel 2: 512 threads, TQ=4, 8 keys/thread -----------------
// R11's mask (measured 469 µs, clean counters) with qvT b128 broadcast.
// Keys k = 2048c + 4t + j (c in {0,1}); acc[2][4][4] = 32 f32 (clean shape).
// Phase 2: float-domain bisection (R9-R16 verified); bitmap output (R8).
__global__ __launch_bounds__(512, 2)
void hp_mask_v17(const float* __restrict__ lf, const float* __restrict__ gfT,
                 unsigned short* __restrict__ out)
{
    __shared__ float qvT[ID][TQ];                 // [d][qi], 1 KiB
    __shared__ float lq[TQ][ID];                  // 1 KiB
    __shared__ unsigned long long red[4][8];      // buf0,buf1,greater,equal
    __shared__ unsigned int bitmap[TQ][SEQ / 32]; // 2 KiB selection bitmap
    __shared__ float lsc[TQ][LW];
    __shared__ unsigned char tm[512];             // rare tie path: 8 keys/thr

    const int tid = threadIdx.x;
    const int lane = tid & 63, w = tid >> 6;      // 8 waves
    const int bq = blockIdx.x;            // b*(SEQ/TQ) + qgroup
    const int b = bq >> 10;
    const int q0 = (bq & 1023) * TQ;
    const float* gTb = gfT + (long)b * ID * SEQ;
    const float* lfb = lf + (long)b * SEQ * ID;

    if (tid < 256) {   // qvT[d][qi] = gfT[b][d][q0+qi]; lq from lf rows
        int d = tid >> 2, qi = tid & 3;
        qvT[d][qi] = gTb[(long)d * SEQ + q0 + qi];
        int qi2 = tid >> 6, d2 = tid & 63;
        lq[qi2][d2] = lfb[(long)(q0 + qi2) * ID + d2];
    }
    ((unsigned int*)bitmap)[tid] = 0u;            // 512 words exactly
    __syncthreads();

    // ---- Phase 1: register-resident scores, 2-stream 1-deep prefetch --------
    float acc[2][4][TQ];                  // [c][j][qi] = 32 f32
#pragma unroll
    for (int c = 0; c < 2; c++)
#pragma unroll
        for (int j = 0; j < 4; j++)
#pragma unroll
            for (int qi = 0; qi < TQ; qi++) acc[c][j][qi] = 0.f;

    const float4* gT4 = (const float4*)gTb;
    float4 ka = gT4[tid], kb = gT4[512 + tid];
#pragma unroll 1
    for (int d = 0; d < ID; d++) {
        float4 na, nb;
        if (d + 1 < ID) {
            na = gT4[((d + 1) << 10) + tid];
            nb = gT4[((d + 1) << 10) + 512 + tid];
        }
        const float4 qd4 = *(const float4*)&qvT[d][0];   // uniform b128 read
        float qd[TQ];
        qd[0] = qd4.x; qd[1] = qd4.y; qd[2] = qd4.z; qd[3] = qd4.w;
#pragma unroll
        for (int qi = 0; qi < TQ; qi++) {
            acc[0][0][qi] = fmaf(ka.x, qd[qi], acc[0][0][qi]);
            acc[0][1][qi] = fmaf(ka.y, qd[qi], acc[0][1][qi]);
            acc[0][2][qi] = fmaf(ka.z, qd[qi], acc[0][2][qi]);
            acc[0][3][qi] = fmaf(ka.w, qd[qi], acc[0][3][qi]);
            acc[1][0][qi] = fmaf(kb.x, qd[qi], acc[1][0][qi]);
            acc[1][1][qi] = fmaf(kb.y, qd[qi], acc[1][1][qi]);
            acc[1][2][qi] = fmaf(kb.z, qd[qi], acc[1][2][qi]);
            acc[1][3][qi] = fmaf(kb.w, qd[qi], acc[1][3][qi]);
        }
        ka = na; kb = nb;
    }

    // ---- Phase 2a: in-place keys: sv = banned ? -1 : relu(s) ----------------
#pragma unroll
    for (int c = 0; c < 2; c++)
#pragma unroll
        for (int j = 0; j < 4; j++) {
            const int k = 2048 * c + 4 * tid + j;
#pragma unroll
            for (int qi = 0; qi < TQ; qi++) {
                const int q = q0 + qi;
                const bool banned = (k <= q) && (k >= q - (LW - 1));
                acc[c][j][qi] = banned ? -1.0f : fmaxf(acc[c][j][qi], 0.f);
            }
        }

    // ---- Phase 2b: bisection for m32 in u-space, compares in float ----------
    // u = bits(sv)+1; u>=m <=> sv >= uint_as_float(m-1). 31 trials close
    // [0, 0x7F800000] to width <= 1; lo converges to m32 (R9-R16 verified).
    unsigned int lo[TQ], hi[TQ];
#pragma unroll
    for (int qi = 0; qi < TQ; qi++) { lo[qi] = 0u; hi[qi] = 0x7F800000u; }

#pragma unroll 1
    for (int it = 0; it < 31; ++it) {
        unsigned long long pc = 0ull;
#pragma unroll
        for (int qi = 0; qi < TQ; qi++) {
            const unsigned int mid = lo[qi] + ((hi[qi] - lo[qi]) >> 1);
            const float tf = __uint_as_float(mid - 1u);
            int cnt = 0;
#pragma unroll
            for (int c = 0; c < 2; c++)
#pragma unroll
                for (int j = 0; j < 4; j++)
                    cnt += __popcll(__ballot(acc[c][j][qi] >= tf));
            pc |= (unsigned long long)(unsigned int)cnt << (16 * qi);
        }
        if (lane == 0) red[it & 1][w] = pc;
        __syncthreads();
        unsigned long long tot = 0ull;
#pragma unroll
        for (int ww = 0; ww < 8; ww++) tot += red[it & 1][ww];
#pragma unroll
        for (int qi = 0; qi < TQ; qi++) {
            const unsigned int mid = lo[qi] + ((hi[qi] - lo[qi]) >> 1);
            const unsigned int cnt =
                (unsigned int)((tot >> (16 * qi)) & 0xFFFFull);
            if (cnt >= GK) lo[qi] = mid; else hi[qi] = mid;
        }
    }

    // ---- Phase 2c: C1 = #{u > m32}, T = #{u == m32} -------------------------
    int T[TQ], need[TQ];
    {
        unsigned long long pg = 0ull, pe = 0ull;
#pragma unroll
        for (int qi = 0; qi < TQ; qi++) {
            const float tg = __uint_as_float(lo[qi]);   // u>lo <=> sv>=float(lo)
            const unsigned int eb = lo[qi] - 1u;        // u==lo <=> bits(sv)==eb
            int cg = 0, ce = 0;
#pragma unroll
            for (int c = 0; c < 2; c++)
#pragma unroll
                for (int j = 0; j < 4; j++) {
                    const float v = acc[c][j][qi];
                    cg += __popcll(__ballot(v >= tg));
                    ce += __popcll(__ballot(__float_as_uint(v) == eb));
                }
            pg |= (unsigned long long)(unsigned int)cg << (16 * qi);
            pe |= (unsigned long long)(unsigned int)ce << (16 * qi);
        }
        if (lane == 0) { red[2][w] = pg; red[3][w] = pe; }
        __syncthreads();
        unsigned long long tg = 0ull, te = 0ull;
#pragma unroll
        for (int ww = 0; ww < 8; ww++) { tg += red[2][ww]; te += red[3][ww]; }
#pragma unroll
        for (int qi = 0; qi < TQ; qi++) {
            const int c1 = (int)((tg >> (16 * qi)) & 0xFFFFull);
            T[qi]    = (int)((te >> (16 * qi)) & 0xFFFFull);
            need[qi] = GK - c1;               // >= 1; T >= need guaranteed
        }
    }

    // ---- Phase 2d: mark selections in bitmap --------------------------------
#pragma unroll
    for (int qi = 0; qi < TQ; qi++) {
        const bool allties = (T[qi] == need[qi]);
        const float tg = __uint_as_float(lo[qi]);
        const unsigned int eb = lo[qi] - 1u;
#pragma unroll
        for (int c = 0; c < 2; c++)
#pragma unroll
            for (int j = 0; j < 4; j++) {
                const float v = acc[c][j][qi];
                const bool sel_ = (v >= tg)
                                | (allties & (__float_as_uint(v) == eb));
                if (sel_) {
                    const int k = 2048 * c + 4 * tid + j;
                    atomicOr(&bitmap[qi][k >> 5], 1u << (k & 31));
                }
            }
    }

    // Rare exact-tie path: pick the `need` smallest-k ties ascending
    // (k = 2048c + 4t + j increases lexicographically in (c, t, j)).
#pragma unroll 1
    for (int qi = 0; qi < TQ; qi++) {
        if (T[qi] > need[qi]) {           // block-uniform (T,need from shared)
            const unsigned int eb = lo[qi] - 1u;
            unsigned int m8 = 0u;
#pragma unroll
            for (int c = 0; c < 2; c++)
#pragma unroll
                for (int j = 0; j < 4; j++)
                    if (__float_as_uint(acc[c][j][qi]) == eb)
                        m8 |= 1u << (c * 4 + j);
            tm[tid] = (unsigned char)m8;
            __syncthreads();
            if (tid == 0) {
                int taken = 0;
                for (int c = 0; c < 2 && taken < need[qi]; c++)
                    for (int t = 0; t < 512 && taken < need[qi]; t++) {
                        const unsigned int nib = ((unsigned int)tm[t] >> (c * 4)) & 15u;
                        for (int j = 0; j < 4 && taken < need[qi]; j++)
                            if ((nib >> j) & 1u) {
                                const int k = 2048 * c + 4 * t + j;
                                atomicOr(&bitmap[qi][k >> 5], 1u << (k & 31));
                                taken++;
                            }
                    }
            }
            __syncthreads();
        }
    }

    // ---- local window: 16 scores per query, stable top-ks -> bitmap ---------
    if (tid < TQ * LW) {
        int qi = tid >> 4, wnd = tid & 15;
        int q = q0 + qi;
        int win = q - (LW - 1) + wnd;
        float v = NEG_INF;
        if (win >= 0) {
            const float4* kr = (const float4*)(lfb + (long)win * ID);
            float s = 0.f;
#pragma unroll
            for (int d = 0; d < 16; d++) {
                float4 kvv = kr[d];
                const float4 qd = *(const float4*)&lq[qi][d * 4];
                s = fmaf(kvv.x, qd.x, s); s = fmaf(kvv.y, qd.y, s);
                s = fmaf(kvv.z, qd.z, s); s = fmaf(kvv.w, qd.w, s);
            }
            v = fmaxf(s, 0.f);
        }
        lsc[qi][wnd] = v;
    }
    __syncthreads();
    if (tid < TQ) {
        int qi = tid, q = q0 + qi;
        int L = (q + 1 < LW) ? q + 1 : LW;
        int ks = L / 5; if (ks < 1) ks = 1;   // == max(1, int(L*0.2))
        for (int t = 0; t < ks; t++) {
            float best = NEG_INF; int bi = 0;
            for (int wnd = 0; wnd < LW; wnd++) {
                float v = lsc[qi][wnd];
                if (v > best) { best = v; bi = wnd; }  // strict > keeps lowest idx
            }
            lsc[qi][bi] = NEG_INF;
            const int win = q - (LW - 1) + bi;
            atomicOr(&bitmap[qi][win >> 5], 1u << (win & 31));
        }
    }
    __syncthreads();

    // ---- output: single-pass fill from bitmap (each line written once) ------
    uint4* orow = (uint4*)(out + ((long)b * SEQ + q0) * SEQ);
#pragma unroll
    for (int i = 0; i < TQ * SEQ / 8 / 512; i++) {  // 4 iters, 2048 uint4
        const int li = i * 512 + tid;
        const int qi = li >> 9;          // 512 uint4 per row
        const int w8 = li & 511;         // cols 8*w8 .. 8*w8+7
        const unsigned int bits =
            (bitmap[qi][w8 >> 2] >> ((w8 & 3) * 8)) & 0xFFu;
        uint4 v;
        v.x = MASKED4 & ~(((bits &   1u) ? 0x0000FFFFu : 0u) |
                          ((bits &   2u) ? 0xFFFF0000u : 0u));
        v.y = MASKED4 & ~(((bits &   4u) ? 0x0000FFFFu : 0u) |
                          ((bits &   8u) ? 0xFFFF0000u : 0u));
        v.z = MASKED4 & ~(((bits &  16u) ? 0x0000FFFFu : 0u) |
                          ((bits &  32u) ? 0xFFFF0000u : 0u));
        v.w = MASKED4 & ~(((bits &  64u) ? 0x0000FFFFu : 0u) |
                          ((bits & 128u) ? 0xFFFF0000u : 0u));
        orow[li] = v;
    }
}

extern "C" void kernel_launch(void* const* d_in, const int* in_sizes, int n_in,
                              void* d_out, int out_size, void* d_ws, size_t ws_size,
                              hipStream_t stream) {
    const unsigned short* x  = (const unsigned short*)d_in[0];
    const unsigned short* Wl = (const unsigned short*)d_in[1];
    // d_in[2] = W_medium: dead in the reference — skipped.
    const unsigned short* Wg = (const unsigned short*)d_in[3];
    unsigned short* out = (unsigned short*)d_out;

    float* lf  = (float*)d_ws;                        // 4 MiB, row-major
    float* gfT = lf + (long)FMAT;                     // 4 MiB, [b][d][s]

    hp_feat_v14<<<NB * SEQ / 16, 512, 0, stream>>>(x, Wl, Wg, lf, gfT);
    hp_mask_v17<<<NB * SEQ / TQ, 512, 0, stream>>>(lf, gfT, out);
}

// Round 11
// 715.382 us; speedup vs baseline: 3.0433x; 1.0075x over previous
//
// HierarchicalPattern — rev18. R17 consolidation confirmed (total 720.7, mask
// 446 clean: FETCH 27 MB, WRITE 131 MB, VGPR 36, Occ 66%). Budget: 206 µs
// harness + ~68 feat + 446 mask. Mask streams 4.3 GB / 446 µs = 9.6 TB/s =
// L3 plateau while VALUBusy*dur = 277 µs -> memory slightly ahead of VALU.
// One unconfounded lever left: XCD batch-pinning on the CLEAN structure
// (R12-R14 bundled it with spilling kernels; never isolated). Each batch's
// gfT = 4 MB = exactly one XCD L2; pinning xcd=bid&7 -> b=xcd>>1 makes each
// XCD re-read one resident set -> L2-mostly stream (34.5 TB/s aggregate).
// ONLY change vs rev17 is the mask block->(b,qg) bijection (R12-verified).
// Predict: mask 300-350 (VALUBusy -> 85-90%) if dispatch round-robins XCDs;
// neutral 440-450 if not -> then declare roofline (all other levers hit
// measured walls: spill at >32 f32 live, 1024-thr penalty, exact-selection).
#include <hip/hip_runtime.h>
#include <hip/hip_fp16.h>
#include <cstdint>

#define SEQ 4096
#define NB 4
#define DMODEL 1024
#define ID 64
#define LW 16
#define GK 32
#define TQ 4

#define NEG_INF (-__builtin_inff())
#define MASKED4 0xFBFFFBFFu
#define FMAT (NB * SEQ * ID)          // floats per feature matrix (4 MiB)

typedef _Float16 f16x8 __attribute__((ext_vector_type(8)));
typedef float f32x4 __attribute__((ext_vector_type(4)));

// ---------------- Kernel 1: lf + gfT via MFMA (fp16 in, f32 out) -------------
// feat_v14 verbatim (~68 µs; floor ~30). grid 1024 x 512thr; wave w: half=w&1
// (0=lf,1=gfT), ch=w>>1 (16-col quarter). D-layout col=l&15, row=(l>>4)*4+reg.
__global__ __launch_bounds__(512)
void hp_feat_v14(const unsigned short* __restrict__ xu,
                 const unsigned short* __restrict__ Wlu,
                 const unsigned short* __restrict__ Wgu,
                 float* __restrict__ lf, float* __restrict__ gfT)
{
    const int tid = threadIdx.x;
    const int lane = tid & 63, w = tid >> 6;      // 8 waves
    const long row0 = (long)blockIdx.x * 16;
    const int half = w & 1;
    const int ch = w >> 1;                        // 0..3, 16 cols each
    const _Float16* xp = (const _Float16*)xu;
    const _Float16* Wp = (const _Float16*)(half ? Wgu : Wlu);

    const int lr = lane & 15;          // row-in-tile (A) / col-in-tile (B,D)
    const int kg = lane >> 4;          // k-group: k offset kg*8

    const _Float16* ap = xp + (row0 + lr) * DMODEL + kg * 8;
    const _Float16* bp = Wp + (long)(ch * 16 + lr) * DMODEL + kg * 8;

    f32x4 acc = (f32x4){0.f, 0.f, 0.f, 0.f};

#pragma unroll 4
    for (int k0 = 0; k0 < DMODEL; k0 += 32) {
        f16x8 av = *(const f16x8*)(ap + k0);
        f16x8 bv = *(const f16x8*)(bp + k0);
        acc = __builtin_amdgcn_mfma_f32_16x16x32_f16(av, bv, acc, 0, 0, 0);
    }

    if (!half) {        // lf[s][d]: 16 lanes = 16 consecutive d
#pragma unroll
        for (int r = 0; r < 4; r++)
            lf[(row0 + kg * 4 + r) * ID + ch * 16 + lr] = acc[r];
    } else {            // gfT[b][d][s]: float4 along s
        const int bb = (int)(row0 >> 12), s0 = (int)(row0 & 4095);
        float4 st = make_float4(acc[0], acc[1], acc[2], acc[3]);
        *(float4*)(gfT + ((long)bb * ID + ch * 16 + lr) * SEQ + s0 + kg * 4) = st;
    }
}

// ---------------- Kernel 2: 512 threads, TQ=4, 8 keys/thread -----------------
// rev17 mask + XCD batch-pinning bijection (the ONLY change): xcd=bid&7,
// b=xcd>>1, qg=((bid>>3)<<1)|(xcd&1). Keys k = 2048c+4t+j; acc[2][4][4]=32
// f32 (clean). Float-domain bisection (R9-R17 verified); bitmap output (R8).
__global__ __launch_bounds__(512, 2)
void hp_mask_v18(const float* __restrict__ lf, const float* __restrict__ gfT,
                 unsigned short* __restrict__ out)
{
    __shared__ float qvT[ID][TQ];                 // [d][qi], 1 KiB
    __shared__ float lq[TQ][ID];                  // 1 KiB
    __shared__ unsigned long long red[4][8];      // buf0,buf1,greater,equal
    __shared__ unsigned int bitmap[TQ][SEQ / 32]; // 2 KiB selection bitmap
    __shared__ float lsc[TQ][LW];
    __shared__ unsigned char tm[512];             // rare tie path: 8 keys/thr

    const int tid = threadIdx.x;
    const int lane = tid & 63, w = tid >> 6;      // 8 waves
    const int bid = blockIdx.x;                   // 4096 blocks
    const int xcd = bid & 7;
    const int b = xcd >> 1;                       // batch pinned to XCD pair
    const int qg = ((bid >> 3) << 1) | (xcd & 1); // 0..1023
    const int q0 = qg * TQ;
    const float* gTb = gfT + (long)b * ID * SEQ;
    const float* lfb = lf + (long)b * SEQ * ID;

    if (tid < 256) {   // qvT[d][qi] = gfT[b][d][q0+qi]; lq from lf rows
        int d = tid >> 2, qi = tid & 3;
        qvT[d][qi] = gTb[(long)d * SEQ + q0 + qi];
        int qi2 = tid >> 6, d2 = tid & 63;
        lq[qi2][d2] = lfb[(long)(q0 + qi2) * ID + d2];
    }
    ((unsigned int*)bitmap)[tid] = 0u;            // 512 words exactly
    __syncthreads();

    // ---- Phase 1: register-resident scores, 2-stream 1-deep prefetch --------
    float acc[2][4][TQ];                  // [c][j][qi] = 32 f32
#pragma unroll
    for (int c = 0; c < 2; c++)
#pragma unroll
        for (int j = 0; j < 4; j++)
#pragma unroll
            for (int qi = 0; qi < TQ; qi++) acc[c][j][qi] = 0.f;

    const float4* gT4 = (const float4*)gTb;
    float4 ka = gT4[tid], kb = gT4[512 + tid];
#pragma unroll 1
    for (int d = 0; d < ID; d++) {
        float4 na, nb;
        if (d + 1 < ID) {
            na = gT4[((d + 1) << 10) + tid];
            nb = gT4[((d + 1) << 10) + 512 + tid];
        }
        const float4 qd4 = *(const float4*)&qvT[d][0];   // uniform b128 read
        float qd[TQ];
        qd[0] = qd4.x; qd[1] = qd4.y; qd[2] = qd4.z; qd[3] = qd4.w;
#pragma unroll
        for (int qi = 0; qi < TQ; qi++) {
            acc[0][0][qi] = fmaf(ka.x, qd[qi], acc[0][0][qi]);
            acc[0][1][qi] = fmaf(ka.y, qd[qi], acc[0][1][qi]);
            acc[0][2][qi] = fmaf(ka.z, qd[qi], acc[0][2][qi]);
            acc[0][3][qi] = fmaf(ka.w, qd[qi], acc[0][3][qi]);
            acc[1][0][qi] = fmaf(kb.x, qd[qi], acc[1][0][qi]);
            acc[1][1][qi] = fmaf(kb.y, qd[qi], acc[1][1][qi]);
            acc[1][2][qi] = fmaf(kb.z, qd[qi], acc[1][2][qi]);
            acc[1][3][qi] = fmaf(kb.w, qd[qi], acc[1][3][qi]);
        }
        ka = na; kb = nb;
    }

    // ---- Phase 2a: in-place keys: sv = banned ? -1 : relu(s) ----------------
#pragma unroll
    for (int c = 0; c < 2; c++)
#pragma unroll
        for (int j = 0; j < 4; j++) {
            const int k = 2048 * c + 4 * tid + j;
#pragma unroll
            for (int qi = 0; qi < TQ; qi++) {
                const int q = q0 + qi;
                const bool banned = (k <= q) && (k >= q - (LW - 1));
                acc[c][j][qi] = banned ? -1.0f : fmaxf(acc[c][j][qi], 0.f);
            }
        }

    // ---- Phase 2b: bisection for m32 in u-space, compares in float ----------
    // u = bits(sv)+1; u>=m <=> sv >= uint_as_float(m-1). 31 trials close
    // [0, 0x7F800000] to width <= 1; lo converges to m32 (R9-R17 verified).
    unsigned int lo[TQ], hi[TQ];
#pragma unroll
    for (int qi = 0; qi < TQ; qi++) { lo[qi] = 0u; hi[qi] = 0x7F800000u; }

#pragma unroll 1
    for (int it = 0; it < 31; ++it) {
        unsigned long long pc = 0ull;
#pragma unroll
        for (int qi = 0; qi < TQ; qi++) {
            const unsigned int mid = lo[qi] + ((hi[qi] - lo[qi]) >> 1);
            const float tf = __uint_as_float(mid - 1u);
            int cnt = 0;
#pragma unroll
            for (int c = 0; c < 2; c++)
#pragma unroll
                for (int j = 0; j < 4; j++)
                    cnt += __popcll(__ballot(acc[c][j][qi] >= tf));
            pc |= (unsigned long long)(unsigned int)cnt << (16 * qi);
        }
        if (lane == 0) red[it & 1][w] = pc;
        __syncthreads();
        unsigned long long tot = 0ull;
#pragma unroll
        for (int ww = 0; ww < 8; ww++) tot += red[it & 1][ww];
#pragma unroll
        for (int qi = 0; qi < TQ; qi++) {
            const unsigned int mid = lo[qi] + ((hi[qi] - lo[qi]) >> 1);
            const unsigned int cnt =
                (unsigned int)((tot >> (16 * qi)) & 0xFFFFull);
            if (cnt >= GK) lo[qi] = mid; else hi[qi] = mid;
        }
    }

    // ---- Phase 2c: C1 = #{u > m32}, T = #{u == m32} -------------------------
    int T[TQ], need[TQ];
    {
        unsigned long long pg = 0ull, pe = 0ull;
#pragma unroll
        for (int qi = 0; qi < TQ; qi++) {
            const float tg = __uint_as_float(lo[qi]);   // u>lo <=> sv>=float(lo)
            const unsigned int eb = lo[qi] - 1u;        // u==lo <=> bits(sv)==eb
            int cg = 0, ce = 0;
#pragma unroll
            for (int c = 0; c < 2; c++)
#pragma unroll
                for (int j = 0; j < 4; j++) {
                    const float v = acc[c][j][qi];
                    cg += __popcll(__ballot(v >= tg));
                    ce += __popcll(__ballot(__float_as_uint(v) == eb));
                }
            pg |= (unsigned long long)(unsigned int)cg << (16 * qi);
            pe |= (unsigned long long)(unsigned int)ce << (16 * qi);
        }
        if (lane == 0) { red[2][w] = pg; red[3][w] = pe; }
        __syncthreads();
        unsigned long long tg = 0ull, te = 0ull;
#pragma unroll
        for (int ww = 0; ww < 8; ww++) { tg += red[2][ww]; te += red[3][ww]; }
#pragma unroll
        for (int qi = 0; qi < TQ; qi++) {
            const int c1 = (int)((tg >> (16 * qi)) & 0xFFFFull);
            T[qi]    = (int)((te >> (16 * qi)) & 0xFFFFull);
            need[qi] = GK - c1;               // >= 1; T >= need guaranteed
        }
    }

    // ---- Phase 2d: mark selections in bitmap --------------------------------
#pragma unroll
    for (int qi = 0; qi < TQ; qi++) {
        const bool allties = (T[qi] == need[qi]);
        const float tg = __uint_as_float(lo[qi]);
        const unsigned int eb = lo[qi] - 1u;
#pragma unroll
        for (int c = 0; c < 2; c++)
#pragma unroll
            for (int j = 0; j < 4; j++) {
                const float v = acc[c][j][qi];
                const bool sel_ = (v >= tg)
                                | (allties & (__float_as_uint(v) == eb));
                if (sel_) {
                    const int k = 2048 * c + 4 * tid + j;
                    atomicOr(&bitmap[qi][k >> 5], 1u << (k & 31));
                }
            }
    }

    // Rare exact-tie path: pick the `need` smallest-k ties ascending
    // (k = 2048c + 4t + j increases lexicographically in (c, t, j)).
#pragma unroll 1
    for (int qi = 0; qi < TQ; qi++) {
        if (T[qi] > need[qi]) {           // block-uniform (T,need from shared)
            const unsigned int eb = lo[qi] - 1u;
            unsigned int m8 = 0u;
#pragma unroll
            for (int c = 0; c < 2; c++)
#pragma unroll
                for (int j = 0; j < 4; j++)
                    if (__float_as_uint(acc[c][j][qi]) == eb)
                        m8 |= 1u << (c * 4 + j);
            tm[tid] = (unsigned char)m8;
            __syncthreads();
            if (tid == 0) {
                int taken = 0;
                for (int c = 0; c < 2 && taken < need[qi]; c++)
                    for (int t = 0; t < 512 && taken < need[qi]; t++) {
                        const unsigned int nib = ((unsigned int)tm[t] >> (c * 4)) & 15u;
                        for (int j = 0; j < 4 && taken < need[qi]; j++)
                            if ((nib >> j) & 1u) {
                                const int k = 2048 * c + 4 * t + j;
                                atomicOr(&bitmap[qi][k >> 5], 1u << (k & 31));
                                taken++;
                            }
                    }
            }
            __syncthreads();
        }
    }

    // ---- local window: 16 scores per query, stable top-ks -> bitmap ---------
    if (tid < TQ * LW) {
        int qi = tid >> 4, wnd = tid & 15;
        int q = q0 + qi;
        int win = q - (LW - 1) + wnd;
        float v = NEG_INF;
        if (win >= 0) {
            const float4* kr = (const float4*)(lfb + (long)win * ID);
            float s = 0.f;
#pragma unroll
            for (int d = 0; d < 16; d++) {
                float4 kvv = kr[d];
                const float4 qd = *(const float4*)&lq[qi][d * 4];
                s = fmaf(kvv.x, qd.x, s); s = fmaf(kvv.y, qd.y, s);
                s = fmaf(kvv.z, qd.z, s); s = fmaf(kvv.w, qd.w, s);
            }
            v = fmaxf(s, 0.f);
        }
        lsc[qi][wnd] = v;
    }
    __syncthreads();
    if (tid < TQ) {
        int qi = tid, q = q0 + qi;
        int L = (q + 1 < LW) ? q + 1 : LW;
        int ks = L / 5; if (ks < 1) ks = 1;   // == max(1, int(L*0.2))
        for (int t = 0; t < ks; t++) {
            float best = NEG_INF; int bi = 0;
            for (int wnd = 0; wnd < LW; wnd++) {
                float v = lsc[qi][wnd];
                if (v > best) { best = v; bi = wnd; }  // strict > keeps lowest idx
            }
            lsc[qi][bi] = NEG_INF;
            const int win = q - (LW - 1) + bi;
            atomicOr(&bitmap[qi][win >> 5], 1u << (win & 31));
        }
    }
    __syncthreads();

    // ---- output: single-pass fill from bitmap (each line written once) ------
    uint4* orow = (uint4*)(out + ((long)b * SEQ + q0) * SEQ);
#pragma unroll
    for (int i = 0; i < TQ * SEQ / 8 / 512; i++) {  // 4 iters, 2048 uint4
        const int li = i * 512 + tid;
        const int qi = li >> 9;          // 512 uint4 per row
        const int w8 = li & 511;         // cols 8*w8 .. 8*w8+7
        const unsigned int bits =
            (bitmap[qi][w8 >> 2] >> ((w8 & 3) * 8)) & 0xFFu;
        uint4 v;
        v.x = MASKED4 & ~(((bits &   1u) ? 0x0000FFFFu : 0u) |
                          ((bits &   2u) ? 0xFFFF0000u : 0u));
        v.y = MASKED4 & ~(((bits &   4u) ? 0x0000FFFFu : 0u) |
                          ((bits &   8u) ? 0xFFFF0000u : 0u));
        v.z = MASKED4 & ~(((bits &  16u) ? 0x0000FFFFu : 0u) |
                          ((bits &  32u) ? 0xFFFF0000u : 0u));
        v.w = MASKED4 & ~(((bits &  64u) ? 0x0000FFFFu : 0u) |
                          ((bits & 128u) ? 0xFFFF0000u : 0u));
        orow[li] = v;
    }
}

extern "C" void kernel_launch(void* const* d_in, const int* in_sizes, int n_in,
                              void* d_out, int out_size, void* d_ws, size_t ws_size,
                              hipStream_t stream) {
    const unsigned short* x  = (const unsigned short*)d_in[0];
    const unsigned short* Wl = (const unsigned short*)d_in[1];
    // d_in[2] = W_medium: dead in the reference — skipped.
    const unsigned short* Wg = (const unsigned short*)d_in[3];
    unsigned short* out = (unsigned short*)d_out;

    float* lf  = (float*)d_ws;                        // 4 MiB, row-major
    float* gfT = lf + (long)FMAT;                     // 4 MiB, [b][d][s]

    hp_feat_v14<<<NB * SEQ / 16, 512, 0, stream>>>(x, Wl, Wg, lf, gfT);
    hp_mask_v18<<<NB * SEQ / TQ, 512, 0, stream>>>(lf, gfT, out);
}